// Round 1
// baseline (25891.345 us; speedup 1.0000x reference)
//
#include <hip/hip_runtime.h>
#include <math.h>

// GRU: T=512, B=64, H=512, L=2, all fp32.
// Phase 1 per layer: Gx[t][j][b] = (In @ [W_ir|W_iz|W_in])[t*64+b][j] + folded biases
//   (j in [0,1536): gate = j>>9; biases: r: b_ir+b_hr, z: b_iz+b_hz, n: b_in)
// Phase 2 per layer: persistent 256-block kernel, weight-stationary W_h slice in LDS,
//   one device-scope grid barrier per timestep, h ping-ponged in [k][b] layout.

// ---------------------------------------------------------------- grid barrier
__device__ __forceinline__ void grid_barrier(unsigned* bar, unsigned target) {
  __syncthreads();  // drains each wave's vmcnt -> this block's stores are in L2
  if (threadIdx.x == 0) {
    __threadfence();  // agent-scope release: flush local L2 so other XCDs can see
    unsigned* cnt = bar;       // cacheline 0
    unsigned* gen = bar + 32;  // cacheline 1
    unsigned prev = __hip_atomic_fetch_add(cnt, 1u, __ATOMIC_ACQ_REL,
                                           __HIP_MEMORY_SCOPE_AGENT);
    if (prev == (unsigned)(gridDim.x - 1)) {
      __hip_atomic_store(cnt, 0u, __ATOMIC_RELAXED, __HIP_MEMORY_SCOPE_AGENT);
      __hip_atomic_store(gen, target, __ATOMIC_RELEASE, __HIP_MEMORY_SCOPE_AGENT);
    } else {
      while (__hip_atomic_load(gen, __ATOMIC_ACQUIRE,
                               __HIP_MEMORY_SCOPE_AGENT) < target) {
        __builtin_amdgcn_s_sleep(1);
      }
    }
  }
  __syncthreads();
}

// ---------------------------------------------------------------- prep
// hT[k*64+b] = init[b*512+k]; zero the barrier words. grid 128 x 256.
__global__ void gru_prep(const float* __restrict__ init, float* __restrict__ hT,
                         unsigned* __restrict__ bar) {
  int idx = blockIdx.x * 256 + threadIdx.x;  // 0..32767
  int k = idx >> 6, b = idx & 63;
  hT[idx] = init[b * 512 + k];
  if (idx < 64) bar[idx] = 0u;
}

// ---------------------------------------------------------------- input GEMM
// A: layer0 = x as [row=t*64+b][k] row-major; layer1 (aT=1) = Y0t as [t][k][b].
// Gx out: [tl][j][b] (t-local to chunk). Block = 128 rows x 64 cols, BK=16.
__global__ __launch_bounds__(256, 2) void gru_gemm(
    const float* __restrict__ A,
    const float* __restrict__ Wr, const float* __restrict__ Wz,
    const float* __restrict__ Wn,
    const float* __restrict__ bir, const float* __restrict__ bhr,
    const float* __restrict__ biz, const float* __restrict__ bhz,
    const float* __restrict__ bin_,
    float* __restrict__ Gx, int t0, int aT) {
  __shared__ float As[16][132];  // [k][m], +4 pad breaks store conflicts
  __shared__ float Bs[16][64];
  const int tid = threadIdx.x;
  const int n0 = blockIdx.x * 64;           // 0..1535
  const int m0g = t0 * 64 + blockIdx.y * 128;  // global row base
  const int gate = n0 >> 9;                 // uniform per block (64 | 512)
  const float* W = (gate == 0) ? Wr : (gate == 1) ? Wz : Wn;
  const int cW = n0 & 511;
  const int tx = tid & 15, ty = tid >> 4;
  float acc[8][4];
#pragma unroll
  for (int i = 0; i < 8; ++i)
#pragma unroll
    for (int j = 0; j < 4; ++j) acc[i][j] = 0.0f;

  for (int kt = 0; kt < 512; kt += 16) {
    __syncthreads();
    if (!aT) {
#pragma unroll
      for (int p = 0; p < 2; ++p) {
        int id = tid + p * 256;
        int row = id >> 2, kq = (id & 3) << 2;
        const float4 v =
            *(const float4*)(A + (size_t)(m0g + row) * 512 + kt + kq);
        As[kq + 0][row] = v.x;
        As[kq + 1][row] = v.y;
        As[kq + 2][row] = v.z;
        As[kq + 3][row] = v.w;
      }
    } else {
#pragma unroll
      for (int p = 0; p < 2; ++p) {
        int id = tid + p * 256;
        int tt = id >> 8, k = (id >> 4) & 15, b4 = (id & 15) << 2;
        int tg = (m0g >> 6) + tt;
        const float4 v =
            *(const float4*)(A + ((size_t)tg * 512 + kt + k) * 64 + b4);
        *(float4*)(&As[k][tt * 64 + b4]) = v;
      }
    }
    {
      int k = tid >> 4, c4 = (tid & 15) << 2;
      *(float4*)(&Bs[k][c4]) =
          *(const float4*)(W + (size_t)(kt + k) * 512 + cW + c4);
    }
    __syncthreads();
#pragma unroll
    for (int k = 0; k < 16; ++k) {
      const float4 a0 = *(const float4*)(&As[k][ty * 8]);
      const float4 a1 = *(const float4*)(&As[k][ty * 8 + 4]);
      const float4 bv = *(const float4*)(&Bs[k][tx * 4]);
      float a[8] = {a0.x, a0.y, a0.z, a0.w, a1.x, a1.y, a1.z, a1.w};
#pragma unroll
      for (int i = 0; i < 8; ++i) {
        acc[i][0] += a[i] * bv.x;
        acc[i][1] += a[i] * bv.y;
        acc[i][2] += a[i] * bv.z;
        acc[i][3] += a[i] * bv.w;
      }
    }
  }
  float bias[4];
#pragma unroll
  for (int jj = 0; jj < 4; ++jj) {
    int cc = cW + tx * 4 + jj;
    bias[jj] = (gate == 0) ? (bir[cc] + bhr[cc])
               : (gate == 1) ? (biz[cc] + bhz[cc])
                             : bin_[cc];
  }
#pragma unroll
  for (int i = 0; i < 8; ++i) {
    int rowg = m0g + ty * 8 + i;
    int b = rowg & 63, tl = (rowg >> 6) - t0;
    float* gp = Gx + ((size_t)tl * 1536 + n0 + tx * 4) * 64 + b;
    gp[0] = acc[i][0] + bias[0];
    gp[64] = acc[i][1] + bias[1];
    gp[128] = acc[i][2] + bias[2];
    gp[192] = acc[i][3] + bias[3];
  }
}

// ---------------------------------------------------------------- recurrence
// 256 blocks x 256 threads, persistent over [t0,t1). Block owns hidden cols
// cg0..cg0+1 (x3 gates) of W_h, kept in LDS. h kept as hT[k][b] ping-pong.
// Thread (s=tid&15, ks=tid>>4): batches s*4..+3, k-range ks*32..+31, 6 dot-cols.
__global__ __launch_bounds__(256, 1) void gru_recur(
    const float* __restrict__ Gx,  // [chunkT][1536][64]
    const float* __restrict__ Whr, const float* __restrict__ Whz,
    const float* __restrict__ Whn, const float* __restrict__ bhn,
    float* hT0, float* hT1, float* __restrict__ Yout,
    float* __restrict__ finals, unsigned* bar, int t0, int t1,
    int transpose_out) {
  __shared__ float wsh[512][8];      // [k][c*4+g], g=0..2 (r,z,n), slot3 pad
  __shared__ float red[16][16][28];  // [ks][s][24 used]
  __shared__ float ghfin[6][64];     // [c*3+g][b]
  const int tid = threadIdx.x;
  const int cg0 = blockIdx.x * 2;
  for (int idx = tid; idx < 4096; idx += 256) {
    int k = idx >> 3, slot = idx & 7;
    int c = slot >> 2, g = slot & 3;
    float v = 0.0f;
    if (g == 0) v = Whr[k * 512 + cg0 + c];
    else if (g == 1) v = Whz[k * 512 + cg0 + c];
    else if (g == 2) v = Whn[k * 512 + cg0 + c];
    wsh[k][slot] = v;
  }
  __syncthreads();
  const int s = tid & 15, ks = tid >> 4;
  const int b0 = s << 2;
  const int k0 = ks << 5;

  for (int t = t0; t < t1; ++t) {
    const float* hcur = (t & 1) ? hT1 : hT0;
    float* hnext = (t & 1) ? hT0 : hT1;
    float acc[6][4];
#pragma unroll
    for (int d = 0; d < 6; ++d)
#pragma unroll
      for (int i = 0; i < 4; ++i) acc[d][i] = 0.0f;

#pragma unroll 8
    for (int kk = 0; kk < 32; ++kk) {
      int k = k0 + kk;
      const float4 h4 = *(const float4*)(hcur + k * 64 + b0);
      const float4 wA = *(const float4*)(&wsh[k][0]);
      const float4 wB = *(const float4*)(&wsh[k][4]);
      acc[0][0] += h4.x * wA.x; acc[0][1] += h4.y * wA.x;
      acc[0][2] += h4.z * wA.x; acc[0][3] += h4.w * wA.x;
      acc[1][0] += h4.x * wA.y; acc[1][1] += h4.y * wA.y;
      acc[1][2] += h4.z * wA.y; acc[1][3] += h4.w * wA.y;
      acc[2][0] += h4.x * wA.z; acc[2][1] += h4.y * wA.z;
      acc[2][2] += h4.z * wA.z; acc[2][3] += h4.w * wA.z;
      acc[3][0] += h4.x * wB.x; acc[3][1] += h4.y * wB.x;
      acc[3][2] += h4.z * wB.x; acc[3][3] += h4.w * wB.x;
      acc[4][0] += h4.x * wB.y; acc[4][1] += h4.y * wB.y;
      acc[4][2] += h4.z * wB.y; acc[4][3] += h4.w * wB.y;
      acc[5][0] += h4.x * wB.z; acc[5][1] += h4.y * wB.z;
      acc[5][2] += h4.z * wB.z; acc[5][3] += h4.w * wB.z;
    }
    {
      float* rb = &red[ks][s][0];
#pragma unroll
      for (int d = 0; d < 6; ++d)
        *(float4*)(rb + d * 4) =
            make_float4(acc[d][0], acc[d][1], acc[d][2], acc[d][3]);
    }
    __syncthreads();
    for (int v = tid; v < 384; v += 256) {
      int so = v / 24;
      int rem = v - so * 24;
      float sum = 0.0f;
#pragma unroll
      for (int q = 0; q < 16; ++q) sum += red[q][so][rem];
      ghfin[rem >> 2][(so << 2) | (rem & 3)] = sum;
    }
    __syncthreads();
    if (tid < 128) {
      int b = tid & 63, c = tid >> 6;
      int cg = cg0 + c;
      const float* gx = Gx + (size_t)(t - t0) * 1536 * 64;
      float gr = ghfin[c * 3 + 0][b];
      float gz = ghfin[c * 3 + 1][b];
      float gn = ghfin[c * 3 + 2][b];
      float xr = gx[(0 * 512 + cg) * 64 + b];
      float xz = gx[(1 * 512 + cg) * 64 + b];
      float xn = gx[(2 * 512 + cg) * 64 + b];
      float hp = hcur[cg * 64 + b];
      float r = 1.0f / (1.0f + expf(-(xr + gr)));
      float z = 1.0f / (1.0f + expf(-(xz + gz)));
      float n = tanhf(xn + r * (gn + bhn[cg]));
      float hv = (1.0f - z) * n + z * hp;
      hnext[cg * 64 + b] = hv;
      if (transpose_out)
        Yout[((size_t)t * 512 + cg) * 64 + b] = hv;  // layer0: [t][h][b]
      else
        Yout[((size_t)t * 64 + b) * 512 + cg] = hv;  // layer1: [t][b][h]
      if (t == 511) finals[b * 512 + cg] = hv;
    }
    grid_barrier(bar, (unsigned)(t + 1));
  }
}

// ---------------------------------------------------------------- launch
extern "C" void kernel_launch(void* const* d_in, const int* in_sizes, int n_in,
                              void* d_out, int out_size, void* d_ws,
                              size_t ws_size, hipStream_t stream) {
  const float* x = (const float*)d_in[0];
  const float* init = (const float*)d_in[1];
  const float* w_ir = (const float*)d_in[2];
  const float* w_hr = (const float*)d_in[3];
  const float* w_iz = (const float*)d_in[4];
  const float* w_hz = (const float*)d_in[5];
  const float* w_in_ = (const float*)d_in[6];
  const float* w_hn = (const float*)d_in[7];
  const float* b_ir = (const float*)d_in[8];
  const float* b_hr = (const float*)d_in[9];
  const float* b_iz = (const float*)d_in[10];
  const float* b_hz = (const float*)d_in[11];
  const float* b_in_ = (const float*)d_in[12];
  const float* b_hn = (const float*)d_in[13];
  float* out = (float*)d_out;
  float* Y = out;                                  // [T,B,H] region
  float* finals = out + (size_t)512 * 64 * 512;    // [L,B,H] region

  // Chunk the Gx buffer to fit the workspace.
  int chunks = 1;
  while (chunks < 256) {
    size_t need = ((size_t)(512 / chunks) * 64 * 1536 + 2 * 32768 + 64) * 4;
    if (need <= ws_size) break;
    chunks <<= 1;
  }
  int chunkT = 512 / chunks;
  float* wsf = (float*)d_ws;
  float* Gx = wsf;
  float* hT0 = wsf + (size_t)chunkT * 64 * 1536;
  float* hT1 = hT0 + 32768;
  unsigned* bar = (unsigned*)(hT1 + 32768);

  for (int l = 0; l < 2; ++l) {
    const float* inA = (l == 0) ? x : Y;  // layer1 reads Y0t staged in d_out
    int aT = (l == 0) ? 0 : 1;
    size_t wOff = (size_t)l * 512 * 512;
    size_t bOff = (size_t)l * 512;
    gru_prep<<<128, 256, 0, stream>>>(init + (size_t)l * 32768, hT0, bar);
    for (int c = 0; c < chunks; ++c) {
      int t0 = c * chunkT;
      gru_gemm<<<dim3(24, chunkT / 2), 256, 0, stream>>>(
          inA, w_ir + wOff, w_iz + wOff, w_in_ + wOff, b_ir + bOff,
          b_hr + bOff, b_iz + bOff, b_hz + bOff, b_in_ + bOff, Gx, t0, aT);
      gru_recur<<<256, 256, 0, stream>>>(
          Gx, w_hr + wOff, w_hz + wOff, w_hn + wOff, b_hn + bOff, hT0, hT1, Y,
          finals + (size_t)l * 32768, bar, t0, t0 + chunkT, (l == 0) ? 1 : 0);
    }
  }
}

// Round 2
// 10989.571 us; speedup vs baseline: 2.3560x; 2.3560x over previous
//
#include <hip/hip_runtime.h>
#include <math.h>

// GRU: T=512, B=64, H=512, L=2, fp32.
// Phase 1 per layer: Gx[t][j][b] = (In @ [W_ir|W_iz|W_in]) + folded biases.
// Phase 2 per layer: persistent 128-block kernel; each block owns 4 hidden
// cols x 3 gates. Weights pre-transposed to wtr[blk][k][16] and read via
// scalar(SMEM) loads; h exchanged through relaxed agent-scope (sc1) atomics;
// fence-free monotone grid barrier (leaf+root counters, never reset).

__device__ __forceinline__ float ldh(const float* p) {
  return __hip_atomic_load(p, __ATOMIC_RELAXED, __HIP_MEMORY_SCOPE_AGENT);
}
__device__ __forceinline__ void sth(float* p, float v) {
  __hip_atomic_store(p, v, __ATOMIC_RELAXED, __HIP_MEMORY_SCOPE_AGENT);
}

// bar layout (unsigned words): leaf counters at bar[leaf*32] (8 leaves),
// root at bar[256], generation at bar[288]. All monotone; prep zeroes 1024.
__device__ __forceinline__ void grid_barrier(unsigned* bar, unsigned target,
                                             unsigned blocks_per_leaf) {
  __syncthreads();  // all waves done; vmcnt(0) => sc1 stores globally visible
  if (threadIdx.x == 0) {
    unsigned leaf = blockIdx.x & 7u;
    unsigned prev = __hip_atomic_fetch_add(bar + leaf * 32, 1u,
                                           __ATOMIC_RELAXED,
                                           __HIP_MEMORY_SCOPE_AGENT);
    bool done = false;
    if ((prev % blocks_per_leaf) == blocks_per_leaf - 1u) {
      unsigned p2 = __hip_atomic_fetch_add(bar + 256, 1u, __ATOMIC_RELAXED,
                                           __HIP_MEMORY_SCOPE_AGENT);
      if ((p2 & 7u) == 7u) {
        __hip_atomic_store(bar + 288, target, __ATOMIC_RELAXED,
                           __HIP_MEMORY_SCOPE_AGENT);
        done = true;
      }
    }
    if (!done) {
      while (__hip_atomic_load(bar + 288, __ATOMIC_RELAXED,
                               __HIP_MEMORY_SCOPE_AGENT) < target) {
        __builtin_amdgcn_s_sleep(1);
      }
    }
  }
  __syncthreads();
}

// ---------------------------------------------------------------- prep
// hT[k*64+b] = init[b*512+k]; zero 1024 barrier words. grid 128 x 256.
__global__ void gru_prep(const float* __restrict__ init, float* __restrict__ hT,
                         unsigned* __restrict__ bar) {
  int idx = blockIdx.x * 256 + threadIdx.x;  // 0..32767
  int k = idx >> 6, b = idx & 63;
  hT[idx] = init[b * 512 + k];
  if (idx < 1024) bar[idx] = 0u;
}

// ---------------------------------------------------------------- weight transpose
// wtr[blk][k][16]: slot = cp*8 + c*3 + g for block cols cg = blk*4 + cp*2 + c.
// grid 128 x 256.
__global__ void gru_wtr(const float* __restrict__ Whr,
                        const float* __restrict__ Whz,
                        const float* __restrict__ Whn,
                        float* __restrict__ wtr) {
  int bk = blockIdx.x;
  int cg0 = bk * 4;
  for (int idx = threadIdx.x; idx < 512 * 12; idx += 256) {
    int k = idx & 511, sl = idx >> 9;  // sl 0..11 = cp*6 + c*3 + g
    int cp = (sl >= 6) ? 1 : 0;
    int r6 = sl - cp * 6;
    int c = (r6 >= 3) ? 1 : 0;
    int g = r6 - c * 3;
    int cg = cg0 + cp * 2 + c;
    const float* W = (g == 0) ? Whr : (g == 1) ? Whz : Whn;
    wtr[((size_t)bk * 512 + k) * 16 + cp * 8 + c * 3 + g] = W[k * 512 + cg];
  }
}

// ---------------------------------------------------------------- input GEMM
// A: layer0 = x as [row=t*64+b][k]; layer1 (aT=1) = Y0t as [t][k][b].
// Gx out: [tl][j][b]. Block = 128 rows x 64 cols, BK=16.
__global__ __launch_bounds__(256, 2) void gru_gemm(
    const float* __restrict__ A,
    const float* __restrict__ Wr, const float* __restrict__ Wz,
    const float* __restrict__ Wn,
    const float* __restrict__ bir, const float* __restrict__ bhr,
    const float* __restrict__ biz, const float* __restrict__ bhz,
    const float* __restrict__ bin_,
    float* __restrict__ Gx, int t0, int aT) {
  __shared__ float As[16][132];
  __shared__ float Bs[16][64];
  const int tid = threadIdx.x;
  const int n0 = blockIdx.x * 64;
  const int m0g = t0 * 64 + blockIdx.y * 128;
  const int gate = n0 >> 9;
  const float* W = (gate == 0) ? Wr : (gate == 1) ? Wz : Wn;
  const int cW = n0 & 511;
  const int tx = tid & 15, ty = tid >> 4;
  float acc[8][4];
#pragma unroll
  for (int i = 0; i < 8; ++i)
#pragma unroll
    for (int j = 0; j < 4; ++j) acc[i][j] = 0.0f;

  for (int kt = 0; kt < 512; kt += 16) {
    __syncthreads();
    if (!aT) {
#pragma unroll
      for (int p = 0; p < 2; ++p) {
        int id = tid + p * 256;
        int row = id >> 2, kq = (id & 3) << 2;
        const float4 v =
            *(const float4*)(A + (size_t)(m0g + row) * 512 + kt + kq);
        As[kq + 0][row] = v.x;
        As[kq + 1][row] = v.y;
        As[kq + 2][row] = v.z;
        As[kq + 3][row] = v.w;
      }
    } else {
#pragma unroll
      for (int p = 0; p < 2; ++p) {
        int id = tid + p * 256;
        int tt = id >> 8, k = (id >> 4) & 15, b4 = (id & 15) << 2;
        int tg = (m0g >> 6) + tt;
        const float4 v =
            *(const float4*)(A + ((size_t)tg * 512 + kt + k) * 64 + b4);
        *(float4*)(&As[k][tt * 64 + b4]) = v;
      }
    }
    {
      int k = tid >> 4, c4 = (tid & 15) << 2;
      *(float4*)(&Bs[k][c4]) =
          *(const float4*)(W + (size_t)(kt + k) * 512 + cW + c4);
    }
    __syncthreads();
#pragma unroll
    for (int k = 0; k < 16; ++k) {
      const float4 a0 = *(const float4*)(&As[k][ty * 8]);
      const float4 a1 = *(const float4*)(&As[k][ty * 8 + 4]);
      const float4 bv = *(const float4*)(&Bs[k][tx * 4]);
      float a[8] = {a0.x, a0.y, a0.z, a0.w, a1.x, a1.y, a1.z, a1.w};
#pragma unroll
      for (int i = 0; i < 8; ++i) {
        acc[i][0] += a[i] * bv.x;
        acc[i][1] += a[i] * bv.y;
        acc[i][2] += a[i] * bv.z;
        acc[i][3] += a[i] * bv.w;
      }
    }
  }
  float bias[4];
#pragma unroll
  for (int jj = 0; jj < 4; ++jj) {
    int cc = cW + tx * 4 + jj;
    bias[jj] = (gate == 0) ? (bir[cc] + bhr[cc])
               : (gate == 1) ? (biz[cc] + bhz[cc])
                             : bin_[cc];
  }
#pragma unroll
  for (int i = 0; i < 8; ++i) {
    int rowg = m0g + ty * 8 + i;
    int b = rowg & 63, tl = (rowg >> 6) - t0;
    float* gp = Gx + ((size_t)tl * 1536 + n0 + tx * 4) * 64 + b;
    gp[0] = acc[i][0] + bias[0];
    gp[64] = acc[i][1] + bias[1];
    gp[128] = acc[i][2] + bias[2];
    gp[192] = acc[i][3] + bias[3];
  }
}

// ---------------------------------------------------------------- recurrence
// 128 blocks x 1024 threads. Block owns cols cg0..cg0+3 (x3 gates).
// Thread: lane b = tid&63; wave wv = tid>>6: ks = wv&7 (k-range 64),
// cp = wv>>3 (col-pair). Weights via scalar loads from wtr (wave-uniform).
__global__ __launch_bounds__(1024, 4) void gru_recur(
    const float* __restrict__ Gx,   // [chunkT][1536][64]
    const float* __restrict__ wtr,  // [128][512][16]
    const float* __restrict__ bhn,
    float* hT0, float* hT1, float* __restrict__ Yout,
    float* __restrict__ finals, unsigned* bar, int t0, int t1,
    int transpose_out) {
  __shared__ float red[16][64][7];   // [wv][b][d], stride 7 => conflict-free
  __shared__ float ghfin[12][64];    // [cp*6 + c*3 + g][b]
  const int tid = threadIdx.x;
  const int b = tid & 63;
  const int wv = __builtin_amdgcn_readfirstlane(tid >> 6);  // 0..15, scalar
  const int ks = wv & 7, cp = wv >> 3;
  const int cg0 = blockIdx.x * 4;
  const float* wp = wtr + (size_t)blockIdx.x * 8192 + cp * 8;  // + k*16
  const int kbase = ks * 64;

  for (int t = t0; t < t1; ++t) {
    float* hc = (t & 1) ? hT1 : hT0;
    float* hn = (t & 1) ? hT0 : hT1;
    float acc0 = 0.f, acc1 = 0.f, acc2 = 0.f, acc3 = 0.f, acc4 = 0.f,
          acc5 = 0.f;
    // 8 interleaved k-streams, 1-round-ahead prefetch => 8-16 loads in flight.
    float hbuf[8];
#pragma unroll
    for (int s = 0; s < 8; ++s) hbuf[s] = ldh(hc + (kbase + s * 8) * 64 + b);
#pragma unroll
    for (int j = 0; j < 8; ++j) {
      float hv[8];
#pragma unroll
      for (int s = 0; s < 8; ++s) hv[s] = hbuf[s];
      if (j < 7) {
#pragma unroll
        for (int s = 0; s < 8; ++s)
          hbuf[s] = ldh(hc + (kbase + s * 8 + j + 1) * 64 + b);
      }
#pragma unroll
      for (int s = 0; s < 8; ++s) {
        const float* wr = wp + (size_t)((kbase + s * 8 + j) << 4);
        acc0 = fmaf(hv[s], wr[0], acc0);
        acc1 = fmaf(hv[s], wr[1], acc1);
        acc2 = fmaf(hv[s], wr[2], acc2);
        acc3 = fmaf(hv[s], wr[3], acc3);
        acc4 = fmaf(hv[s], wr[4], acc4);
        acc5 = fmaf(hv[s], wr[5], acc5);
      }
    }
    {
      float* rp = &red[wv][b][0];
      rp[0] = acc0; rp[1] = acc1; rp[2] = acc2;
      rp[3] = acc3; rp[4] = acc4; rp[5] = acc5;
    }
    __syncthreads();
    if (tid < 768) {  // 12 d-slots x 64 b; sum 8 k-partials
      int bb = tid & 63, rest = tid >> 6;  // rest = cp*6 + d6
      int cpp = (rest >= 6) ? 1 : 0;
      int d6 = rest - cpp * 6;
      float ssum = 0.f;
#pragma unroll
      for (int q = 0; q < 8; ++q) ssum += red[cpp * 8 + q][bb][d6];
      ghfin[rest][bb] = ssum;
    }
    __syncthreads();
    if (tid < 256) {
      int bb = tid & 63, cc = tid >> 6;  // cc 0..3
      int cg = cg0 + cc;
      const float* gx = Gx + (size_t)(t - t0) * 1536 * 64;
      int base = (cc >> 1) * 6 + (cc & 1) * 3;
      float gr = ghfin[base + 0][bb];
      float gz = ghfin[base + 1][bb];
      float gn = ghfin[base + 2][bb];
      float xr = gx[(0 * 512 + cg) * 64 + bb];
      float xz = gx[(1 * 512 + cg) * 64 + bb];
      float xn = gx[(2 * 512 + cg) * 64 + bb];
      float hp = ldh(hc + cg * 64 + bb);
      float r = 1.0f / (1.0f + expf(-(xr + gr)));
      float z = 1.0f / (1.0f + expf(-(xz + gz)));
      float n = tanhf(xn + r * (gn + bhn[cg]));
      float hvv = (1.0f - z) * n + z * hp;
      sth(hn + cg * 64 + bb, hvv);
      if (transpose_out)
        Yout[((size_t)t * 512 + cg) * 64 + bb] = hvv;  // layer0: [t][h][b]
      else
        Yout[((size_t)t * 64 + bb) * 512 + cg] = hvv;  // layer1: [t][b][h]
      if (t == 511) finals[bb * 512 + cg] = hvv;
    }
    grid_barrier(bar, (unsigned)(t + 1), 16u);
  }
}

// ---------------------------------------------------------------- launch
extern "C" void kernel_launch(void* const* d_in, const int* in_sizes, int n_in,
                              void* d_out, int out_size, void* d_ws,
                              size_t ws_size, hipStream_t stream) {
  const float* x = (const float*)d_in[0];
  const float* init = (const float*)d_in[1];
  const float* w_ir = (const float*)d_in[2];
  const float* w_hr = (const float*)d_in[3];
  const float* w_iz = (const float*)d_in[4];
  const float* w_hz = (const float*)d_in[5];
  const float* w_in_ = (const float*)d_in[6];
  const float* w_hn = (const float*)d_in[7];
  const float* b_ir = (const float*)d_in[8];
  const float* b_hr = (const float*)d_in[9];
  const float* b_iz = (const float*)d_in[10];
  const float* b_hz = (const float*)d_in[11];
  const float* b_in_ = (const float*)d_in[12];
  const float* b_hn = (const float*)d_in[13];
  float* out = (float*)d_out;
  float* Y = out;                                // [T,B,H]
  float* finals = out + (size_t)512 * 64 * 512;  // [L,B,H]

  const size_t WTR = (size_t)128 * 512 * 16;  // 1M floats
  int chunks = 1;
  while (chunks < 256) {
    size_t need =
        ((size_t)(512 / chunks) * 64 * 1536 + 2 * 32768 + WTR + 1024) * 4;
    if (need <= ws_size) break;
    chunks <<= 1;
  }
  int chunkT = 512 / chunks;
  float* wsf = (float*)d_ws;
  float* Gx = wsf;
  float* hT0 = wsf + (size_t)chunkT * 64 * 1536;
  float* hT1 = hT0 + 32768;
  float* wtr = hT1 + 32768;
  unsigned* bar = (unsigned*)(wtr + WTR);

  for (int l = 0; l < 2; ++l) {
    const float* inA = (l == 0) ? x : Y;  // layer1 reads Y0t staged in d_out
    int aT = (l == 0) ? 0 : 1;
    size_t wOff = (size_t)l * 512 * 512;
    size_t bOff = (size_t)l * 512;
    gru_prep<<<128, 256, 0, stream>>>(init + (size_t)l * 32768, hT0, bar);
    gru_wtr<<<128, 256, 0, stream>>>(w_hr + wOff, w_hz + wOff, w_hn + wOff,
                                     wtr);
    for (int c = 0; c < chunks; ++c) {
      int t0 = c * chunkT;
      gru_gemm<<<dim3(24, chunkT / 2), 256, 0, stream>>>(
          inA, w_ir + wOff, w_iz + wOff, w_in_ + wOff, b_ir + bOff,
          b_hr + bOff, b_iz + bOff, b_hz + bOff, b_in_ + bOff, Gx, t0, aT);
      gru_recur<<<128, 1024, 0, stream>>>(
          Gx, wtr, b_hn + bOff, hT0, hT1, Y, finals + (size_t)l * 32768, bar,
          t0, t0 + chunkT, (l == 0) ? 1 : 0);
    }
  }
}

// Round 4
// 5570.425 us; speedup vs baseline: 4.6480x; 1.9728x over previous
//
#include <hip/hip_runtime.h>
#include <math.h>

// GRU: T=512, B=64, H=512, L=2.
// Phase 1/layer: Gx[t][j][b] = (In @ [W_ir|W_iz|W_in]) + folded biases (fp32 GEMM).
// Phase 2/layer: persistent 64-block MFMA recurrence. Block owns 8 hidden cols
// x 3 gates (24 rows, padded to 32). Weights = bf16 A-fragments held in VGPRs;
// h = bf16 stored globally in MFMA B-fragment order, read straight from the
// coherence point (sc1) each step; fp32 epilogue; monotone fence-free barrier.

typedef short bf16x8 __attribute__((ext_vector_type(8)));
typedef float f32x4 __attribute__((ext_vector_type(4)));

__device__ __forceinline__ unsigned short f2bf(float f) {
  unsigned u = __builtin_bit_cast(unsigned, f);
  return (unsigned short)((u + 0x7fff + ((u >> 16) & 1)) >> 16);
}
__device__ __forceinline__ unsigned long long ldq(const unsigned long long* p) {
  return __hip_atomic_load(p, __ATOMIC_RELAXED, __HIP_MEMORY_SCOPE_AGENT);
}
__device__ __forceinline__ void stq(unsigned long long* p,
                                    unsigned long long v) {
  __hip_atomic_store(p, v, __ATOMIC_RELAXED, __HIP_MEMORY_SCOPE_AGENT);
}

// fragment-order index: element (k,b) lives at chunk*8 + (k&7), chunk below.
__device__ __forceinline__ int hchunk(int k, int b) {
  return ((b >> 4) * 16 + (k >> 5)) * 64 + ((k >> 3) & 3) * 16 + (b & 15);
}

// bar: leaf counters bar[leaf*32] (8 leaves), root bar[256], gen bar[288].
__device__ __forceinline__ void grid_barrier(unsigned* bar, unsigned target) {
  __syncthreads();  // drains vmcnt(0): sc1 stores visible before arrival
  if (threadIdx.x == 0) {
    unsigned leaf = blockIdx.x & 7u;
    unsigned prev = __hip_atomic_fetch_add(bar + leaf * 32, 1u,
                                           __ATOMIC_RELAXED,
                                           __HIP_MEMORY_SCOPE_AGENT);
    bool done = false;
    if ((prev & 7u) == 7u) {  // 8 blocks per leaf
      unsigned p2 = __hip_atomic_fetch_add(bar + 256, 1u, __ATOMIC_RELAXED,
                                           __HIP_MEMORY_SCOPE_AGENT);
      if ((p2 & 7u) == 7u) {
        __hip_atomic_store(bar + 288, target, __ATOMIC_RELAXED,
                           __HIP_MEMORY_SCOPE_AGENT);
        done = true;
      }
    }
    if (!done) {
      while (__hip_atomic_load(bar + 288, __ATOMIC_RELAXED,
                               __HIP_MEMORY_SCOPE_AGENT) < target) {
        __builtin_amdgcn_s_sleep(1);
      }
    }
  }
  __syncthreads();
}

// ---------------------------------------------------------------- prep
// hx0 <- bf16(init) in fragment order; zero 1024 barrier words. grid 64x512.
__global__ void gru_prep(const float* __restrict__ init,
                         unsigned short* __restrict__ hx0,
                         unsigned* __restrict__ bar) {
  int idx = blockIdx.x * 512 + threadIdx.x;  // 0..32767
  int k = idx >> 6, b = idx & 63;
  hx0[hchunk(k, b) * 8 + (k & 7)] = f2bf(init[b * 512 + k]);
  if (idx < 1024) bar[idx] = 0u;
}

// ---------------------------------------------------------------- weight prep
// wtr2[blk][row][k] bf16, row = c*3+g (c=0..7 -> col blk*8+c), rows 24..31 = 0.
__global__ void gru_wtr2(const float* __restrict__ Whr,
                         const float* __restrict__ Whz,
                         const float* __restrict__ Whn,
                         unsigned short* __restrict__ wtr2) {
  int blk = blockIdx.x;
  unsigned short* w = wtr2 + (size_t)blk * 32 * 512;
  for (int idx = threadIdx.x; idx < 32 * 512; idx += 256) {
    int k = idx & 511, row = idx >> 9;
    float v = 0.0f;
    if (row < 24) {
      int c = row / 3, g = row - c * 3;
      int col = blk * 8 + c;
      const float* W = (g == 0) ? Whr : (g == 1) ? Whz : Whn;
      v = W[k * 512 + col];
    }
    w[row * 512 + k] = f2bf(v);
  }
}

// ---------------------------------------------------------------- input GEMM
// A: layer0 = x as [row=t*64+b][k]; layer1 (aT=1) = Y0t as [t][k][b].
// Gx out: [tl][j][b]. Block = 128 rows x 64 cols, BK=16. (unchanged fp32)
__global__ __launch_bounds__(256, 2) void gru_gemm(
    const float* __restrict__ A,
    const float* __restrict__ Wr, const float* __restrict__ Wz,
    const float* __restrict__ Wn,
    const float* __restrict__ bir, const float* __restrict__ bhr,
    const float* __restrict__ biz, const float* __restrict__ bhz,
    const float* __restrict__ bin_,
    float* __restrict__ Gx, int t0, int aT) {
  __shared__ float As[16][132];
  __shared__ float Bs[16][64];
  const int tid = threadIdx.x;
  const int n0 = blockIdx.x * 64;
  const int m0g = t0 * 64 + blockIdx.y * 128;
  const int gate = n0 >> 9;
  const float* W = (gate == 0) ? Wr : (gate == 1) ? Wz : Wn;
  const int cW = n0 & 511;
  const int tx = tid & 15, ty = tid >> 4;
  float acc[8][4];
#pragma unroll
  for (int i = 0; i < 8; ++i)
#pragma unroll
    for (int j = 0; j < 4; ++j) acc[i][j] = 0.0f;

  for (int kt = 0; kt < 512; kt += 16) {
    __syncthreads();
    if (!aT) {
#pragma unroll
      for (int p = 0; p < 2; ++p) {
        int id = tid + p * 256;
        int row = id >> 2, kq = (id & 3) << 2;
        const float4 v =
            *(const float4*)(A + (size_t)(m0g + row) * 512 + kt + kq);
        As[kq + 0][row] = v.x;
        As[kq + 1][row] = v.y;
        As[kq + 2][row] = v.z;
        As[kq + 3][row] = v.w;
      }
    } else {
#pragma unroll
      for (int p = 0; p < 2; ++p) {
        int id = tid + p * 256;
        int tt = id >> 8, k = (id >> 4) & 15, b4 = (id & 15) << 2;
        int tg = (m0g >> 6) + tt;
        const float4 v =
            *(const float4*)(A + ((size_t)tg * 512 + kt + k) * 64 + b4);
        *(float4*)(&As[k][tt * 64 + b4]) = v;
      }
    }
    {
      int k = tid >> 4, c4 = (tid & 15) << 2;
      *(float4*)(&Bs[k][c4]) =
          *(const float4*)(W + (size_t)(kt + k) * 512 + cW + c4);
    }
    __syncthreads();
#pragma unroll
    for (int k = 0; k < 16; ++k) {
      const float4 a0 = *(const float4*)(&As[k][ty * 8]);
      const float4 a1 = *(const float4*)(&As[k][ty * 8 + 4]);
      const float4 bv = *(const float4*)(&Bs[k][tx * 4]);
      float a[8] = {a0.x, a0.y, a0.z, a0.w, a1.x, a1.y, a1.z, a1.w};
#pragma unroll
      for (int i = 0; i < 8; ++i) {
        acc[i][0] += a[i] * bv.x;
        acc[i][1] += a[i] * bv.y;
        acc[i][2] += a[i] * bv.z;
        acc[i][3] += a[i] * bv.w;
      }
    }
  }
  float bias[4];
#pragma unroll
  for (int jj = 0; jj < 4; ++jj) {
    int cc = cW + tx * 4 + jj;
    bias[jj] = (gate == 0) ? (bir[cc] + bhr[cc])
               : (gate == 1) ? (biz[cc] + bhz[cc])
                             : bin_[cc];
  }
#pragma unroll
  for (int i = 0; i < 8; ++i) {
    int rowg = m0g + ty * 8 + i;
    int b = rowg & 63, tl = (rowg >> 6) - t0;
    float* gp = Gx + ((size_t)tl * 1536 + n0 + tx * 4) * 64 + b;
    gp[0] = acc[i][0] + bias[0];
    gp[64] = acc[i][1] + bias[1];
    gp[128] = acc[i][2] + bias[2];
    gp[192] = acc[i][3] + bias[3];
  }
}

// ---------------------------------------------------------------- recurrence
// 64 blocks x 512 threads (8 waves). Wave wv: Nt = wv&3 (16-batch tile),
// Kh = wv>>2 (half of the 16 K-steps). A-frags (weights) VGPR-stationary.
__global__ __launch_bounds__(512, 2) void gru_recur(
    const float* __restrict__ Gx,           // [chunkT][1536][64]
    const unsigned short* __restrict__ wtr2,// [64][32][512] bf16
    const float* __restrict__ bhn,
    const float* __restrict__ init,         // [64][512] fp32 (this layer)
    unsigned short* hx0, unsigned short* hx1,
    float* __restrict__ Yout, float* __restrict__ finals, unsigned* bar,
    int t0, int t1, int layer0) {
  __shared__ float ghp[2][32][66];     // [Kh][row][b] D partials
  __shared__ unsigned short hpack[64 * 8];  // [b][c] new h bf16
  const int tid = threadIdx.x;
  const int lane = tid & 63;
  const int wv = tid >> 6;            // 0..7
  const int Nt = wv & 3, Kh = wv >> 2;
  const int quad = lane >> 4, mm = lane & 15;
  const int cg0 = blockIdx.x * 8;
  // epilogue ids: thread owns (col c = wv, batch bb = lane)
  const int c = wv, bb = lane;
  const int cg = cg0 + c;
  const float bhn_c = bhn[cg];

  // ---- A-fragments (weights), loaded once: 2 Mt x 8 Ksteps x 16B
  bf16x8 a0[8], a1[8];
  {
    const unsigned short* wb = wtr2 + (size_t)blockIdx.x * 32 * 512;
#pragma unroll
    for (int j = 0; j < 8; ++j) {
      int ks = Kh * 8 + j;
      a0[j] = *(const bf16x8*)(wb + (size_t)mm * 512 + ks * 32 + quad * 8);
      a1[j] =
          *(const bf16x8*)(wb + (size_t)(16 + mm) * 512 + ks * 32 + quad * 8);
    }
  }
  // ---- fp32 h_prev for my (cg, bb), recovered across chunk relaunches
  float hp;
  if (t0 == 0) {
    hp = init[bb * 512 + cg];
  } else if (layer0) {
    hp = Yout[((size_t)(t0 - 1) * 512 + cg) * 64 + bb];
  } else {
    hp = Yout[((size_t)(t0 - 1) * 64 + bb) * 512 + cg];
  }

  for (int t = t0; t < t1; ++t) {
    const unsigned short* hc = (t & 1) ? hx1 : hx0;
    unsigned short* hn = (t & 1) ? hx0 : hx1;
    const float* gxt = Gx + (size_t)(t - t0) * 1536 * 64;
    // Gx prefetch (independent of h)
    float xr = gxt[(0 * 512 + cg) * 64 + bb];
    float xz = gxt[(1 * 512 + cg) * 64 + bb];
    float xn = gxt[(2 * 512 + cg) * 64 + bb];
    // ---- B-fragments: 16 independent sc1 8B loads straight from IC
    unsigned long long q0[8], q1[8];
    {
      const unsigned long long* hq = (const unsigned long long*)hc;
#pragma unroll
      for (int j = 0; j < 8; ++j) {
        int ks = Kh * 8 + j;
        const unsigned long long* p = hq + (((Nt * 16 + ks) * 64 + lane) << 1);
        q0[j] = ldq(p);
        q1[j] = ldq(p + 1);
      }
    }
    // ---- MFMA: two 16x16 output tiles (rows 0..15 / 16..23)
    f32x4 acc0 = {0.f, 0.f, 0.f, 0.f}, acc1 = {0.f, 0.f, 0.f, 0.f};
#pragma unroll
    for (int j = 0; j < 8; ++j) {
      union { unsigned long long q[2]; bf16x8 v; } u;
      u.q[0] = q0[j];
      u.q[1] = q1[j];
      acc0 = __builtin_amdgcn_mfma_f32_16x16x32_bf16(a0[j], u.v, acc0, 0, 0, 0);
      acc1 = __builtin_amdgcn_mfma_f32_16x16x32_bf16(a1[j], u.v, acc1, 0, 0, 0);
    }
    // ---- D -> LDS partials (C/D: col=lane&15, row=quad*4+reg)
    {
      float* g = &ghp[Kh][0][0];
      int ncol = Nt * 16 + mm;
#pragma unroll
      for (int r = 0; r < 4; ++r) g[(quad * 4 + r) * 66 + ncol] = acc0[r];
      if (quad < 2) {
#pragma unroll
        for (int r = 0; r < 4; ++r)
          g[(16 + quad * 4 + r) * 66 + ncol] = acc1[r];
      }
    }
    __syncthreads();
    // ---- epilogue: one (cg, bb) per thread, fp32
    {
      float gr = ghp[0][c * 3 + 0][bb] + ghp[1][c * 3 + 0][bb];
      float gz = ghp[0][c * 3 + 1][bb] + ghp[1][c * 3 + 1][bb];
      float gn = ghp[0][c * 3 + 2][bb] + ghp[1][c * 3 + 2][bb];
      float r = 1.0f / (1.0f + expf(-(xr + gr)));
      float z = 1.0f / (1.0f + expf(-(xz + gz)));
      float n = tanhf(xn + r * (gn + bhn_c));
      float hnew = (1.0f - z) * n + z * hp;
      hp = hnew;
      hpack[bb * 8 + c] = f2bf(hnew);
      if (layer0)
        Yout[((size_t)t * 512 + cg) * 64 + bb] = hnew;  // [t][h][b]
      else
        Yout[((size_t)t * 64 + bb) * 512 + cg] = hnew;  // [t][b][h]
      if (t == 511) finals[bb * 512 + cg] = hnew;
    }
    __syncthreads();
    // ---- publish h bf16: one 16B fragment-chunk per batch (wave 0)
    if (tid < 64) {
      int ck = ((tid >> 4) * 16 + (cg0 >> 5)) * 64 + ((cg0 >> 3) & 3) * 16 +
               (tid & 15);
      const unsigned long long* src = (const unsigned long long*)(hpack + tid * 8);
      unsigned long long* dst = (unsigned long long*)(hn + (size_t)ck * 8);
      stq(dst, src[0]);
      stq(dst + 1, src[1]);
    }
    grid_barrier(bar, (unsigned)(t + 1));
  }
}

// ---------------------------------------------------------------- launch
extern "C" void kernel_launch(void* const* d_in, const int* in_sizes, int n_in,
                              void* d_out, int out_size, void* d_ws,
                              size_t ws_size, hipStream_t stream) {
  const float* x = (const float*)d_in[0];
  const float* init = (const float*)d_in[1];
  const float* w_ir = (const float*)d_in[2];
  const float* w_hr = (const float*)d_in[3];
  const float* w_iz = (const float*)d_in[4];
  const float* w_hz = (const float*)d_in[5];
  const float* w_in_ = (const float*)d_in[6];
  const float* w_hn = (const float*)d_in[7];
  const float* b_ir = (const float*)d_in[8];
  const float* b_hr = (const float*)d_in[9];
  const float* b_iz = (const float*)d_in[10];
  const float* b_hz = (const float*)d_in[11];
  const float* b_in_ = (const float*)d_in[12];
  const float* b_hn = (const float*)d_in[13];
  float* out = (float*)d_out;
  float* Y = out;                                // [T,B,H]
  float* finals = out + (size_t)512 * 64 * 512;  // [L,B,H]

  const size_t WTR = (size_t)64 * 32 * 512;  // ushorts (2 MB)
  int chunks = 1;
  while (chunks < 256) {
    size_t need = (size_t)(512 / chunks) * 64 * 1536 * 4 +
                  (size_t)2 * 32768 * 2 + WTR * 2 + 4096;
    if (need <= ws_size) break;
    chunks <<= 1;
  }
  int chunkT = 512 / chunks;
  float* Gx = (float*)d_ws;
  unsigned short* hx0 = (unsigned short*)(Gx + (size_t)chunkT * 1536 * 64);
  unsigned short* hx1 = hx0 + 32768;
  unsigned short* wtr2 = hx1 + 32768;
  unsigned* bar = (unsigned*)(wtr2 + WTR);

  for (int l = 0; l < 2; ++l) {
    const float* inA = (l == 0) ? x : Y;  // layer1 reads Y0t staged in d_out
    int aT = (l == 0) ? 0 : 1;
    size_t wOff = (size_t)l * 512 * 512;
    size_t bOff = (size_t)l * 512;
    gru_prep<<<64, 512, 0, stream>>>(init + (size_t)l * 32768, hx0, bar);
    gru_wtr2<<<64, 256, 0, stream>>>(w_hr + wOff, w_hz + wOff, w_hn + wOff,
                                     wtr2);
    for (int c = 0; c < chunks; ++c) {
      int t0 = c * chunkT;
      gru_gemm<<<dim3(24, chunkT / 2), 256, 0, stream>>>(
          inA, w_ir + wOff, w_iz + wOff, w_in_ + wOff, b_ir + bOff,
          b_hr + bOff, b_iz + bOff, b_hz + bOff, b_in_ + bOff, Gx, t0, aT);
      gru_recur<<<64, 512, 0, stream>>>(
          Gx, wtr2, b_hn + bOff, init + (size_t)l * 32768, hx0, hx1, Y,
          finals + (size_t)l * 32768, bar, t0, t0 + chunkT, (l == 0) ? 1 : 0);
    }
  }
}

// Round 5
// 2565.993 us; speedup vs baseline: 10.0902x; 2.1709x over previous
//
#include <hip/hip_runtime.h>
#include <math.h>

// GRU: T=512, B=64, H=512, L=2. Single persistent fused kernel:
// 128 blocks = 64 layer-0 + 64 layer-1, layer-1 lagging one step (wavefront
// pipeline), 513 grid-barrier steps total. Each block owns 8 hidden cols;
// 32 gate-rows = 8 cols x {r, z, n_x, n_h}. X-projection and H-dot are both
// MFMA (bf16), accumulated into the same D registers (n_x/n_h rows zeroed in
// the respective weight image). Layer-0 X input = pre-transposed bf16 x
// (cached loads); layer-1 X input = layer-0's published bf16 h (sc1 loads).
// h exchanged via relaxed agent-scope (sc1) 8B atomics in MFMA B-fragment
// order; fp32 carry state in registers; monotone fence-free grid barrier.

typedef short bf16x8 __attribute__((ext_vector_type(8)));
typedef float f32x4 __attribute__((ext_vector_type(4)));

__device__ __forceinline__ unsigned short f2bf(float f) {
  unsigned u = __builtin_bit_cast(unsigned, f);
  return (unsigned short)((u + 0x7fff + ((u >> 16) & 1)) >> 16);
}
__device__ __forceinline__ unsigned long long ldq(const unsigned long long* p) {
  return __hip_atomic_load(p, __ATOMIC_RELAXED, __HIP_MEMORY_SCOPE_AGENT);
}
__device__ __forceinline__ void stq(unsigned long long* p,
                                    unsigned long long v) {
  __hip_atomic_store(p, v, __ATOMIC_RELAXED, __HIP_MEMORY_SCOPE_AGENT);
}

// fragment-order: element (k,b) -> chunk*8 + (k&7)
__device__ __forceinline__ int hchunk(int k, int b) {
  return ((b >> 4) * 16 + (k >> 5)) * 64 + ((k >> 3) & 3) * 16 + (b & 15);
}

// bar: leaf counters bar[leaf*32] (8 leaves x 16 blocks), root bar[256],
// gen bar[288]. All monotone; zeroed by prep each launch.
__device__ __forceinline__ void grid_barrier(unsigned* bar, unsigned target) {
  __syncthreads();  // drains vmcnt(0): sc1 stores globally visible
  if (threadIdx.x == 0) {
    unsigned leaf = blockIdx.x & 7u;
    unsigned prev = __hip_atomic_fetch_add(bar + leaf * 32, 1u,
                                           __ATOMIC_RELAXED,
                                           __HIP_MEMORY_SCOPE_AGENT);
    bool done = false;
    if ((prev & 15u) == 15u) {  // 16 blocks per leaf
      unsigned p2 = __hip_atomic_fetch_add(bar + 256, 1u, __ATOMIC_RELAXED,
                                           __HIP_MEMORY_SCOPE_AGENT);
      if ((p2 & 7u) == 7u) {
        __hip_atomic_store(bar + 288, target, __ATOMIC_RELAXED,
                           __HIP_MEMORY_SCOPE_AGENT);
        done = true;
      }
    }
    if (!done) {
      while (__hip_atomic_load(bar + 288, __ATOMIC_RELAXED,
                               __HIP_MEMORY_SCOPE_AGENT) < target) {
        __builtin_amdgcn_s_sleep(1);
      }
    }
  }
  __syncthreads();
}

// ---------------------------------------------------------------- prep
// h0buf[0]/h1buf[0] <- bf16(init) fragment order; zero barrier. grid 128x512.
__global__ void gru_prep_h(const float* __restrict__ init,
                           unsigned short* __restrict__ h0buf,
                           unsigned short* __restrict__ h1buf,
                           unsigned* __restrict__ bar) {
  int l = blockIdx.x >> 6;
  int idx = (blockIdx.x & 63) * 512 + threadIdx.x;  // 0..32767
  int k = idx >> 6, b = idx & 63;
  unsigned short v = f2bf(init[(size_t)l * 32768 + b * 512 + k]);
  unsigned short* dst = (l == 0) ? h0buf : h1buf;
  dst[hchunk(k, b) * 8 + (k & 7)] = v;
  if (blockIdx.x == 0 && threadIdx.x < 512) bar[threadIdx.x] = 0u;
}

// ---------------------------------------------------------------- x transpose
// xbf[t][ck*8+e] = bf16(x[t][b][k]) in fragment order. grid 512(t) x 512.
__global__ void gru_xprep(const float* __restrict__ x,
                          unsigned short* __restrict__ xbf) {
  int t = blockIdx.x;
#pragma unroll
  for (int it = 0; it < 8; ++it) {
    int ck = it * 512 + threadIdx.x;  // 0..4095
    int b = (ck >> 10) * 16 + (ck & 15);
    int k0 = ((ck >> 6) & 15) * 32 + ((ck >> 4) & 3) * 8;
    const float* src = x + ((size_t)t * 64 + b) * 512 + k0;
    float4 v0 = *(const float4*)(src);
    float4 v1 = *(const float4*)(src + 4);
    unsigned short o[8] = {f2bf(v0.x), f2bf(v0.y), f2bf(v0.z), f2bf(v0.w),
                           f2bf(v1.x), f2bf(v1.y), f2bf(v1.z), f2bf(v1.w)};
    *(uint4*)(xbf + (size_t)t * 32768 + ck * 8) = *(const uint4*)o;
  }
}

// ---------------------------------------------------------------- weight images
// wX/wH[l][blk][row][k] bf16, row = c*4+q, col = blk*8+c.
// wX rows: q={Wir,Wiz,Win,0}; wH rows: q={Whr,Whz,0,Whn}. grid 128 x 256.
__global__ void gru_wimg(const float* __restrict__ Wir,
                         const float* __restrict__ Wiz,
                         const float* __restrict__ Win,
                         const float* __restrict__ Whr,
                         const float* __restrict__ Whz,
                         const float* __restrict__ Whn,
                         unsigned short* __restrict__ wX,
                         unsigned short* __restrict__ wH) {
  int l = blockIdx.x >> 6, blk = blockIdx.x & 63;
  size_t base = ((size_t)l * 64 + blk) * 32 * 512;
  size_t wbase = (size_t)l * 512 * 512;
  for (int idx = threadIdx.x; idx < 16384; idx += 256) {
    int c = idx & 7, k = (idx >> 3) & 511, q = idx >> 12;
    int col = blk * 8 + c;
    int row = c * 4 + q;
    size_t we = wbase + (size_t)k * 512 + col;
    float vx = 0.f, vh = 0.f;
    if (q == 0) { vx = Wir[we]; vh = Whr[we]; }
    else if (q == 1) { vx = Wiz[we]; vh = Whz[we]; }
    else if (q == 2) { vx = Win[we]; }
    else { vh = Whn[we]; }
    wX[base + (size_t)row * 512 + k] = f2bf(vx);
    wH[base + (size_t)row * 512 + k] = f2bf(vh);
  }
}

// ---------------------------------------------------------------- fused recurrence
// 128 blocks x 512 threads. role = blk>>6 (0: layer0, 1: layer1 lag-1).
// Wave wv: Nt = wv&3 (16-batch tile), Kh = wv>>2 (K half). A-frags in VGPRs.
__global__ __launch_bounds__(512, 2) void gru_recur_fused(
    const unsigned short* __restrict__ xbf,  // [512][32768]
    const unsigned short* __restrict__ wX,   // [2][64][32][512]
    const unsigned short* __restrict__ wH,
    const float* __restrict__ bir, const float* __restrict__ bhr,
    const float* __restrict__ biz, const float* __restrict__ bhz,
    const float* __restrict__ bin_, const float* __restrict__ bhn,
    const float* __restrict__ init,  // [2][64][512]
    unsigned short* h0buf, unsigned short* h1buf,  // [2][32768] each
    float* __restrict__ Yout, float* __restrict__ finals, unsigned* bar) {
  __shared__ float ghp[2][32][66];          // [Kh][row][b]
  __shared__ unsigned short hpack[64 * 8];  // [b][c]
  const int tid = threadIdx.x;
  const int lane = tid & 63;
  const int wv = tid >> 6;  // 0..7
  const int Nt = wv & 3, Kh = wv >> 2;
  const int quad = lane >> 4, mm = lane & 15;
  const int role = blockIdx.x >> 6;  // block-uniform
  const int blk = blockIdx.x & 63;
  const int cg0 = blk * 8;
  const int c = wv, bb = lane;
  const int cg = cg0 + c;
  const float bR = bir[role * 512 + cg] + bhr[role * 512 + cg];
  const float bZ = biz[role * 512 + cg] + bhz[role * 512 + cg];
  const float bNX = bin_[role * 512 + cg];
  const float bNH = bhn[role * 512 + cg];

  // ---- A-fragments: X-image and H-image, 2 Mtiles x 8 Ksteps each
  bf16x8 aX0[8], aX1[8], aH0[8], aH1[8];
  {
    const unsigned short* wXb = wX + ((size_t)role * 64 + blk) * 32 * 512;
    const unsigned short* wHb = wH + ((size_t)role * 64 + blk) * 32 * 512;
#pragma unroll
    for (int j = 0; j < 8; ++j) {
      int ko = (Kh * 8 + j) * 32 + quad * 8;
      aX0[j] = *(const bf16x8*)(wXb + (size_t)mm * 512 + ko);
      aX1[j] = *(const bf16x8*)(wXb + (size_t)(16 + mm) * 512 + ko);
      aH0[j] = *(const bf16x8*)(wHb + (size_t)mm * 512 + ko);
      aH1[j] = *(const bf16x8*)(wHb + (size_t)(16 + mm) * 512 + ko);
    }
  }
  float hp = init[(size_t)role * 32768 + bb * 512 + cg];

  for (int s = 0; s <= 512; ++s) {
    const bool active = (role == 0) ? (s < 512) : (s >= 1);
    if (active) {
      const int t = (role == 0) ? s : s - 1;
      const unsigned long long* Xq =
          (const unsigned long long*)((role == 0)
                                          ? (xbf + (size_t)t * 32768)
                                          : (h0buf + (size_t)(s & 1) * 32768));
      const unsigned long long* Hq =
          (const unsigned long long*)((role == 0)
                                          ? (h0buf + (size_t)(s & 1) * 32768)
                                          : (h1buf + (size_t)(t & 1) * 32768));
      unsigned short* Hdst = (role == 0)
                                 ? (h0buf + (size_t)((s + 1) & 1) * 32768)
                                 : (h1buf + (size_t)((t + 1) & 1) * 32768);
      // ---- B-fragment loads (all independent, in flight together)
      unsigned long long xq[16], hq[16];
#pragma unroll
      for (int j = 0; j < 8; ++j) {
        int base = ((Nt * 16 + Kh * 8 + j) * 64 + lane) << 1;
        if (role == 0) {  // cached loads (static xbf)
          xq[2 * j] = Xq[base];
          xq[2 * j + 1] = Xq[base + 1];
        } else {  // sc1 (published h0)
          xq[2 * j] = ldq(Xq + base);
          xq[2 * j + 1] = ldq(Xq + base + 1);
        }
        hq[2 * j] = ldq(Hq + base);
        hq[2 * j + 1] = ldq(Hq + base + 1);
      }
      // ---- MFMA: X-dot + H-dot into same accumulators
      f32x4 acc0 = {0.f, 0.f, 0.f, 0.f}, acc1 = {0.f, 0.f, 0.f, 0.f};
#pragma unroll
      for (int j = 0; j < 8; ++j) {
        union { unsigned long long q[2]; bf16x8 v; } ux, uh;
        ux.q[0] = xq[2 * j]; ux.q[1] = xq[2 * j + 1];
        uh.q[0] = hq[2 * j]; uh.q[1] = hq[2 * j + 1];
        acc0 = __builtin_amdgcn_mfma_f32_16x16x32_bf16(aX0[j], ux.v, acc0, 0, 0, 0);
        acc1 = __builtin_amdgcn_mfma_f32_16x16x32_bf16(aX1[j], ux.v, acc1, 0, 0, 0);
        acc0 = __builtin_amdgcn_mfma_f32_16x16x32_bf16(aH0[j], uh.v, acc0, 0, 0, 0);
        acc1 = __builtin_amdgcn_mfma_f32_16x16x32_bf16(aH1[j], uh.v, acc1, 0, 0, 0);
      }
      // ---- D -> LDS (C/D: col=lane&15, row=quad*4+reg)
      {
        float* g = &ghp[Kh][0][0];
        int ncol = Nt * 16 + mm;
#pragma unroll
        for (int r = 0; r < 4; ++r) g[(quad * 4 + r) * 66 + ncol] = acc0[r];
#pragma unroll
        for (int r = 0; r < 4; ++r)
          g[(16 + quad * 4 + r) * 66 + ncol] = acc1[r];
      }
      __syncthreads();
      // ---- epilogue: thread owns (col c, batch bb)
      {
        float gr = ghp[0][c * 4 + 0][bb] + ghp[1][c * 4 + 0][bb];
        float gz = ghp[0][c * 4 + 1][bb] + ghp[1][c * 4 + 1][bb];
        float gnx = ghp[0][c * 4 + 2][bb] + ghp[1][c * 4 + 2][bb];
        float gnh = ghp[0][c * 4 + 3][bb] + ghp[1][c * 4 + 3][bb];
        float r = 1.0f / (1.0f + expf(-(gr + bR)));
        float z = 1.0f / (1.0f + expf(-(gz + bZ)));
        float n = tanhf(gnx + bNX + r * (gnh + bNH));
        float hnew = (1.0f - z) * n + z * hp;
        hp = hnew;
        hpack[bb * 8 + c] = f2bf(hnew);
        if (role == 1) {
          Yout[((size_t)t * 64 + bb) * 512 + cg] = hnew;
          if (t == 511) finals[32768 + bb * 512 + cg] = hnew;
        } else if (t == 511) {
          finals[bb * 512 + cg] = hnew;
        }
      }
      __syncthreads();
      // ---- publish new h (bf16 fragment order), wave 0
      if (tid < 64) {
        int ck = ((tid >> 4) * 16 + (cg0 >> 5)) * 64 + ((cg0 >> 3) & 3) * 16 +
                 (tid & 15);
        const unsigned long long* src =
            (const unsigned long long*)(hpack + tid * 8);
        unsigned long long* dst = (unsigned long long*)(Hdst + (size_t)ck * 8);
        stq(dst, src[0]);
        stq(dst + 1, src[1]);
      }
    }
    grid_barrier(bar, (unsigned)(s + 1));
  }
}

// ---------------------------------------------------------------- launch
extern "C" void kernel_launch(void* const* d_in, const int* in_sizes, int n_in,
                              void* d_out, int out_size, void* d_ws,
                              size_t ws_size, hipStream_t stream) {
  const float* x = (const float*)d_in[0];
  const float* init = (const float*)d_in[1];
  const float* w_ir = (const float*)d_in[2];
  const float* w_hr = (const float*)d_in[3];
  const float* w_iz = (const float*)d_in[4];
  const float* w_hz = (const float*)d_in[5];
  const float* w_in_ = (const float*)d_in[6];
  const float* w_hn = (const float*)d_in[7];
  const float* b_ir = (const float*)d_in[8];
  const float* b_hr = (const float*)d_in[9];
  const float* b_iz = (const float*)d_in[10];
  const float* b_hz = (const float*)d_in[11];
  const float* b_in_ = (const float*)d_in[12];
  const float* b_hn = (const float*)d_in[13];
  float* out = (float*)d_out;
  float* Y = out;                                // [T,B,H] = layer-1 outputs
  float* finals = out + (size_t)512 * 64 * 512;  // [L,B,H]

  // workspace layout (ushorts unless noted)
  unsigned short* xbf = (unsigned short*)d_ws;            // 512*32768
  unsigned short* wX = xbf + (size_t)512 * 32768;         // 2*64*32*512
  unsigned short* wH = wX + (size_t)2 * 64 * 32 * 512;
  unsigned short* h0buf = wH + (size_t)2 * 64 * 32 * 512; // 2*32768
  unsigned short* h1buf = h0buf + 2 * 32768;
  unsigned* bar = (unsigned*)(h1buf + 2 * 32768);         // 512 words

  gru_prep_h<<<128, 512, 0, stream>>>(init, h0buf, h1buf, bar);
  gru_xprep<<<512, 512, 0, stream>>>(x, xbf);
  gru_wimg<<<128, 256, 0, stream>>>(w_ir, w_iz, w_in_, w_hr, w_hz, w_hn, wX,
                                    wH);
  gru_recur_fused<<<128, 512, 0, stream>>>(
      xbf, wX, wH, b_ir, b_hr, b_iz, b_hz, b_in_, b_hn, init, h0buf, h1buf, Y,
      finals, bar);
}